// Round 7
// baseline (742.484 us; speedup 1.0000x reference)
//
#include <hip/hip_runtime.h>

#define NSEG 16
#define CH   16
#define Bb   2
#define Ss   1024
#define Hh   4096
#define Vv   32000
#define SMm  256
#define Rr   256

#define M_MAIN 2046   // Bb*(Ss-1)
#define M_MATH 512
#define M_REAL 2558
#define M_PAD  2560

#define BM 128
#define BN 128
#define BK 128
#define NT_M (M_PAD/BM)   // 20
#define NT_N (Vv/BN)      // 250
#define KT   (Hh/BK)      // 32
#define NWG  (NT_M*NT_N)  // 5000
#define NQG  (Hh/16)      // 256 global 16-k groups

#define HC   8
#define HCL  (Hh/HC)      // 512
#define PART_STRIDE (Bb*NSEG*CH*Rr)

typedef __attribute__((ext_vector_type(4))) float    floatx4;
typedef __attribute__((ext_vector_type(4))) int      intx4;
typedef __attribute__((ext_vector_type(8))) int      intx8;

#define ASCALE 16.f
#define WSCALE 256.f
#define DESCALE (1.f/(16.f*256.f))

template<bool W>
__device__ __forceinline__ int cvtpk(float a, float b, int old) {
  return __builtin_amdgcn_cvt_pk_fp8_f32(a, b, old, W);
}

__device__ __forceinline__ void gload_lds16(const void* g, void* l) {
  __builtin_amdgcn_global_load_lds((const __attribute__((address_space(1))) void*)g,
                                   (__attribute__((address_space(3))) void*)l, 16, 0, 0);
}

// ---------------- K0a: last_hidden -> fp8 A panel, [qgg][row] 16B groups (rows 0..2045) ----------------
__global__ __launch_bounds__(256) void k_convA(const float* __restrict__ lh, intx4* __restrict__ Aq) {
  int row = blockIdx.x * 256 + threadIdx.x;
  int qgg = blockIdx.y;                     // 0..255
  if (row >= M_MAIN) return;
  int b = row / (Ss - 1), s = row % (Ss - 1);
  const floatx4* src = (const floatx4*)(lh + ((size_t)(b * Ss + s)) * Hh + qgg * 16);
  floatx4 f0 = src[0], f1 = src[1], f2 = src[2], f3 = src[3];
  int p0 = cvtpk<false>(f0[0]*ASCALE, f0[1]*ASCALE, 0); p0 = cvtpk<true>(f0[2]*ASCALE, f0[3]*ASCALE, p0);
  int p1 = cvtpk<false>(f1[0]*ASCALE, f1[1]*ASCALE, 0); p1 = cvtpk<true>(f1[2]*ASCALE, f1[3]*ASCALE, p1);
  int p2 = cvtpk<false>(f2[0]*ASCALE, f2[1]*ASCALE, 0); p2 = cvtpk<true>(f2[2]*ASCALE, f2[3]*ASCALE, p2);
  int p3 = cvtpk<false>(f3[0]*ASCALE, f3[1]*ASCALE, 0); p3 = cvtpk<true>(f3[2]*ASCALE, f3[3]*ASCALE, p3);
  Aq[(size_t)qgg * M_PAD + row] = (intx4){p0, p1, p2, p3};
}

// ---------------- K0w: W fp32 -> fp8 Wf[qgg][v] 16B = W[16qgg..16qgg+15][v] * 256 ----------------
__global__ __launch_bounds__(256) void k_convW(const float* __restrict__ W, intx4* __restrict__ Wf) {
  int v = blockIdx.x * 256 + threadIdx.x;   // 125*256 = 32000 exactly
  int qgg = blockIdx.y;                     // 0..255
  const float* base = W + (size_t)(qgg * 16) * Vv + v;
  int p[4];
  #pragma unroll
  for (int q = 0; q < 4; ++q) {
    float e0 = base[(size_t)(4*q+0) * Vv] * WSCALE;
    float e1 = base[(size_t)(4*q+1) * Vv] * WSCALE;
    float e2 = base[(size_t)(4*q+2) * Vv] * WSCALE;
    float e3 = base[(size_t)(4*q+3) * Vv] * WSCALE;
    int pp = cvtpk<false>(e0, e1, 0);
    p[q] = cvtpk<true>(e2, e3, pp);
  }
  Wf[(size_t)qgg * Vv + v] = (intx4){p[0], p[1], p[2], p[3]};
}

// ---------------- K0b: per-H-chunk partials of inter, x staged in LDS ----------------
__global__ __launch_bounds__(256) void k_inter2(const float* __restrict__ kh, const float* __restrict__ Bm,
                                                const int* __restrict__ starts, float* __restrict__ part) {
  int bid = blockIdx.x;                 // Bb*NSEG*HC = 256
  int b = bid >> 7, seg = (bid >> 3) & 15, hc = bid & 7;
  int tid = threadIdx.x;                // = r
  __shared__ float sX[CH][HCL];         // 32 KB
  int st = starts[b];
  for (int i = tid; i < CH * (HCL / 4); i += 256) {
    int c = i / (HCL / 4), k4 = i % (HCL / 4);
    int pos = st + seg * CH + c;
    ((floatx4*)&sX[c][0])[k4] = *(const floatx4*)(kh + ((size_t)(b * Ss + pos)) * Hh + hc * HCL + 4 * k4);
  }
  __syncthreads();
  const floatx4* w = (const floatx4*)(Bm + ((size_t)(seg * Rr + tid)) * Hh + hc * HCL);
  float acc[CH];
  #pragma unroll
  for (int c = 0; c < CH; ++c) acc[c] = 0.f;
  for (int i = 0; i < HCL / 4; ++i) {
    floatx4 w4 = w[i];
    #pragma unroll
    for (int c = 0; c < CH; ++c)
      acc[c] += w4[0]*sX[c][4*i] + w4[1]*sX[c][4*i+1] + w4[2]*sX[c][4*i+2] + w4[3]*sX[c][4*i+3];
  }
  float* dst = part + (size_t)hc * PART_STRIDE + ((size_t)(b * NSEG + seg)) * CH * Rr;
  #pragma unroll
  for (int c = 0; c < CH; ++c) dst[c * Rr + tid] = acc[c];
}

// ---------------- K0c: trans = (sum_hc part) @ A^T + bias -> fp8 A panel rows 2046..2557 ----------------
__global__ __launch_bounds__(256) void k_trans(const float* __restrict__ part, const float* __restrict__ Am,
                                               const float* __restrict__ bias, intx4* __restrict__ Aq) {
  int bid = blockIdx.x;
  int b = bid >> 7, seg = (bid >> 3) & 15, ht = bid & 7;
  int tid = threadIdx.x;
  __shared__ float sI[CH][Rr];
  const float* ib = part + ((size_t)(b * NSEG + seg)) * CH * Rr;
  for (int i = tid; i < CH * Rr / 4; i += 256) {
    floatx4 s = ((const floatx4*)ib)[i];
    #pragma unroll
    for (int hc = 1; hc < HC; ++hc)
      s += ((const floatx4*)(ib + (size_t)hc * PART_STRIDE))[i];
    ((floatx4*)&sI[0][0])[i] = s;
  }
  __syncthreads();
  unsigned char* Ab = (unsigned char*)Aq;
  for (int hh = 0; hh < 2; ++hh) {
    int h = (ht << 9) + (tid << 1) + hh;
    const floatx4* ar = (const floatx4*)(Am + ((size_t)(seg * Hh + h)) * Rr);
    float acc[CH];
    #pragma unroll
    for (int c = 0; c < CH; ++c) acc[c] = 0.f;
    for (int i = 0; i < Rr / 4; ++i) {
      floatx4 a4 = ar[i];
      #pragma unroll
      for (int c = 0; c < CH; ++c)
        acc[c] += a4[0]*sI[c][i*4] + a4[1]*sI[c][i*4+1] + a4[2]*sI[c][i*4+2] + a4[3]*sI[c][i*4+3];
    }
    float bv = bias[seg * Hh + h];
    #pragma unroll
    for (int c = 0; c < CH; ++c) {
      int row = M_MAIN + b * SMm + seg * CH + c;
      int pk = cvtpk<false>((acc[c] + bv) * ASCALE, 0.f, 0);
      Ab[(((size_t)(h >> 4)) * M_PAD + row) * 16 + (h & 15)] = (unsigned char)(pk & 0xFF);
    }
  }
}

// ---------------- K0d: labels, label-logit init, zero fp8 pad rows ----------------
__global__ __launch_bounds__(256) void k_labels(const int* __restrict__ input_ids, const int* __restrict__ mlab,
                                                int* __restrict__ labels, float* __restrict__ llog,
                                                intx4* __restrict__ Aq) {
  int t = blockIdx.x * 256 + threadIdx.x;
  if (t < M_PAD) {
    int lab;
    if (t < M_MAIN)      { int b = t / (Ss - 1), s = t % (Ss - 1); lab = input_ids[b * Ss + s + 1]; }
    else if (t < M_REAL) { lab = mlab[t - M_MAIN]; }
    else                 { lab = 0x7fffffff; }
    labels[t] = lab;
    llog[t] = 0.f;
  }
  if (t < 2 * NQG) {   // zero pad rows 2558,2559 across all 256 qgg
    int qgg = t >> 1, row = M_REAL + (t & 1);
    Aq[(size_t)qgg * M_PAD + row] = (intx4){0, 0, 0, 0};
  }
}

// ---------------- K1: MX-fp8 GEMM, 128x128 tile, 512 thr, 2-buffer counted-vmcnt, 2 blocks/CU ----------------
__global__ __launch_bounds__(512, 4) void k_gemm_mx3(const intx4* __restrict__ Aq, const intx4* __restrict__ Wf,
                                                     const int* __restrict__ labels, float* __restrict__ pmax,
                                                     float* __restrict__ psum, float* __restrict__ llog) {
  __shared__ intx4 As[2][8][BM];    // 32 KB  [buf][qg][row]
  __shared__ intx4 Bs[2][8][BN];    // 32 KB  [buf][qg][col]
  __shared__ float redM[BM * 2];
  __shared__ float redS[BM * 2];

  int bid = blockIdx.x;
  int mt = bid % NT_M, nt = bid / NT_M;   // mt-inner: 20 consecutive blocks share the W panel
  int m0 = mt * BM, n0 = nt * BN;
  int tid = threadIdx.x;
  int lane = tid & 63;
  int wid = tid >> 6;                     // 8 waves: 4 M x 2 N; wave-tile 32x64
  int wr = wid >> 1, wc = wid & 1;
  int l15 = lane & 15, l4 = lane >> 4;

  floatx4 acc[2][4];
  #pragma unroll
  for (int m = 0; m < 2; ++m)
    #pragma unroll
    for (int n = 0; n < 4; ++n) acc[m][n] = (floatx4){0.f, 0.f, 0.f, 0.f};

  // staging: 4 loads/thread/tile (A qg t>>7 and +4; B same), running pointers
  int tq = tid >> 7, tr = tid & 127;      // qg 0..3, row/col 0..127
  const intx4* pA = Aq + (size_t)tq * M_PAD + m0 + tr;
  const intx4* pB = Wf + (size_t)tq * Vv + n0 + tr;

#define STAGE(bb) do {                                        \
    gload_lds16(pA,                 &As[bb][tq][tr]);         \
    gload_lds16(pA + 4 * (size_t)M_PAD, &As[bb][tq + 4][tr]); \
    gload_lds16(pB,                 &Bs[bb][tq][tr]);         \
    gload_lds16(pB + 4 * (size_t)Vv,    &Bs[bb][tq + 4][tr]); \
    pA += 8 * (size_t)M_PAD; pB += 8 * (size_t)Vv;            \
  } while (0)

  STAGE(0);
  STAGE(1);

  for (int kt = 0; kt < KT; ++kt) {
    int cb = kt & 1;
    if (kt < KT - 1) {
      asm volatile("s_waitcnt vmcnt(4)" ::: "memory");   // tile kt's 4 loads (oldest) done; kt+1's in flight
    } else {
      asm volatile("s_waitcnt vmcnt(0)" ::: "memory");
    }
    __builtin_amdgcn_s_barrier();                        // all waves' tile-kt loads landed
    __builtin_amdgcn_sched_barrier(0);

    union frag { intx8 v; struct { intx4 lo, hi; } h; };
    frag a[2], b[4];
    #pragma unroll
    for (int m = 0; m < 2; ++m) {
      int row = wr * 32 + m * 16 + l15;
      a[m].h.lo = As[cb][2 * l4][row];
      a[m].h.hi = As[cb][2 * l4 + 1][row];
    }
    #pragma unroll
    for (int n = 0; n < 4; ++n) {
      int col = wc * 64 + n * 16 + l15;
      b[n].h.lo = Bs[cb][2 * l4][col];
      b[n].h.hi = Bs[cb][2 * l4 + 1][col];
    }

    __builtin_amdgcn_s_setprio(1);
    #pragma unroll
    for (int m = 0; m < 2; ++m)
      #pragma unroll
      for (int n = 0; n < 4; ++n)
        acc[m][n] = __builtin_amdgcn_mfma_scale_f32_16x16x128_f8f6f4(
            a[m].v, b[n].v, acc[m][n], 0, 0, 0, 0x7F7F7F7F, 0, 0x7F7F7F7F);
    __builtin_amdgcn_s_setprio(0);

    __builtin_amdgcn_s_barrier();                        // all waves done reading buf cb
    __builtin_amdgcn_sched_barrier(0);
    if (kt + 2 < KT) STAGE(cb);                          // refill the buffer just freed
  }
#undef STAGE

  // ---- descale (A*16, W*256) ----
  #pragma unroll
  for (int m = 0; m < 2; ++m)
    #pragma unroll
    for (int n = 0; n < 4; ++n) acc[m][n] *= DESCALE;

  // ---- epilogue: label logit scatter; C/D: col=lane&15, row=(lane>>4)*4+reg ----
  #pragma unroll
  for (int m = 0; m < 2; ++m) {
    #pragma unroll
    for (int r = 0; r < 4; ++r) {
      int grow = m0 + wr * 32 + m * 16 + l4 * 4 + r;
      int lab = (grow < M_REAL) ? labels[grow] : -1;
      #pragma unroll
      for (int n = 0; n < 4; ++n) {
        int gcol = n0 + wc * 64 + n * 16 + l15;
        if (lab == gcol) llog[grow] = acc[m][n][r];
      }
    }
  }
  float rm[2][4];
  #pragma unroll
  for (int m = 0; m < 2; ++m)
    #pragma unroll
    for (int r = 0; r < 4; ++r) {
      float v = fmaxf(fmaxf(acc[m][0][r], acc[m][1][r]), fmaxf(acc[m][2][r], acc[m][3][r]));
      v = fmaxf(v, __shfl_xor(v, 1));
      v = fmaxf(v, __shfl_xor(v, 2));
      v = fmaxf(v, __shfl_xor(v, 4));
      v = fmaxf(v, __shfl_xor(v, 8));
      rm[m][r] = v;
    }
  __syncthreads();    // re-sync before redM use (pipeline barriers consumed)
  if (l15 == 0) {
    #pragma unroll
    for (int m = 0; m < 2; ++m)
      #pragma unroll
      for (int r = 0; r < 4; ++r)
        redM[(wr * 32 + m * 16 + l4 * 4 + r) * 2 + wc] = rm[m][r];
  }
  __syncthreads();
  #pragma unroll
  for (int m = 0; m < 2; ++m)
    #pragma unroll
    for (int r = 0; r < 4; ++r) {
      int row = wr * 32 + m * 16 + l4 * 4 + r;
      float tmx = fmaxf(redM[row * 2], redM[row * 2 + 1]);
      float s = 0.f;
      #pragma unroll
      for (int n = 0; n < 4; ++n) s += __expf(acc[m][n][r] - tmx);
      s += __shfl_xor(s, 1);
      s += __shfl_xor(s, 2);
      s += __shfl_xor(s, 4);
      s += __shfl_xor(s, 8);
      rm[m][r] = s;
    }
  if (l15 == 0) {
    #pragma unroll
    for (int m = 0; m < 2; ++m)
      #pragma unroll
      for (int r = 0; r < 4; ++r)
        redS[(wr * 32 + m * 16 + l4 * 4 + r) * 2 + wc] = rm[m][r];
  }
  __syncthreads();
  if (tid < BM) {
    int grow = m0 + tid;
    if (grow < M_REAL) {
      float tmx = fmaxf(redM[tid * 2], redM[tid * 2 + 1]);
      float s = redS[tid * 2] + redS[tid * 2 + 1];
      pmax[(size_t)grow * NT_N + nt] = tmx;
      psum[(size_t)grow * NT_N + nt] = s;
    }
  }
}

// ---------------- K2: combine partials -> nll per row ----------------
__global__ __launch_bounds__(256) void k_fin(const float* __restrict__ pmax, const float* __restrict__ psum,
                                             const float* __restrict__ llog, float* __restrict__ nll) {
  int row = blockIdx.x * 4 + (threadIdx.x >> 6);
  int lane = threadIdx.x & 63;
  if (row >= M_REAL) return;
  float m = -3.4e38f;
  for (int t = lane; t < NT_N; t += 64) m = fmaxf(m, pmax[(size_t)row * NT_N + t]);
  #pragma unroll
  for (int d = 1; d < 64; d <<= 1) m = fmaxf(m, __shfl_xor(m, d));
  float s = 0.f;
  for (int t = lane; t < NT_N; t += 64)
    s += psum[(size_t)row * NT_N + t] * __expf(pmax[(size_t)row * NT_N + t] - m);
  #pragma unroll
  for (int d = 1; d < 64; d <<= 1) s += __shfl_xor(s, d);
  if (lane == 0) nll[row] = logf(s) + m - llog[row];
}

// ---------------- K3: masks, means, A_losses -> 20 outputs ----------------
__global__ __launch_bounds__(256) void k_loss(const float* __restrict__ nll, const int* __restrict__ starts,
                                              const int* __restrict__ ends, const int* __restrict__ attn,
                                              float* __restrict__ out) {
  __shared__ float rA[256], rB[256], rC[256], rD[256];
  __shared__ float smath[M_MATH];
  __shared__ float rl[2];
  int tid = threadIdx.x;
  for (int b = 0; b < 2; ++b) {
    float p = 0.f;
    for (int i = tid; i < Ss; i += 256) p += (float)attn[b * Ss + i];
    rA[tid] = p;
    __syncthreads();
    if (tid == 0) { float t = 0.f; for (int i = 0; i < 256; ++i) t += rA[i]; rl[b] = t; }
    __syncthreads();
  }
  float ss = 0.f, sc = 0.f, fs = 0.f, fc = 0.f;
  int st0 = starts[0], st1 = starts[1], en0 = ends[0], en1 = ends[1];
  for (int r = tid; r < M_MAIN; r += 256) {
    int b = r / (Ss - 1), idx = r % (Ss - 1);
    int st = b ? st1 : st0, en = b ? en1 : en0;
    int rlen = (int)rl[b];
    float v = nll[r];
    if (idx >= st - 1 && idx <= en - 1) { ss += v; sc += 1.f; }
    if (idx >= en && idx < rlen - 1)    { fs += v; fc += 1.f; }
  }
  rA[tid] = ss; rB[tid] = sc; rC[tid] = fs; rD[tid] = fc;
  for (int j = tid; j < M_MATH; j += 256) smath[j] = nll[M_MAIN + j];
  __syncthreads();
  if (tid == 0) {
    float SS = 0.f, SC = 0.f, FS = 0.f, FC = 0.f;
    for (int i = 0; i < 256; ++i) { SS += rA[i]; SC += rB[i]; FS += rC[i]; FC += rD[i]; }
    float MS = 0.f;
    for (int j = 0; j < M_MATH; ++j) MS += smath[j];
    float math_loss = MS / (float)M_MATH;
    float simple = (SC > 0.f) ? SS / fmaxf(SC, 1.f) : 0.f;
    float fin    = (FC > 0.f) ? FS / fmaxf(FC, 1.f) : 0.f;
    out[0] = 0.5f * math_loss + 0.5f * simple + 0.4f * fin;
    out[1] = math_loss;
    out[2] = simple;
    out[3] = fin;
    for (int seg = 0; seg < NSEG; ++seg) {
      float a = 0.f;
      for (int b = 0; b < 2; ++b)
        for (int c = 0; c < CH; ++c) a += smath[b * SMm + seg * CH + c];
      out[4 + seg] = a / 32.f;
    }
  }
}

extern "C" void kernel_launch(void* const* d_in, const int* in_sizes, int n_in,
                              void* d_out, int out_size, void* d_ws, size_t ws_size,
                              hipStream_t stream) {
  const float* k_hidden    = (const float*)d_in[0];
  const float* last_hidden = (const float*)d_in[1];
  const int*   input_ids   = (const int*)d_in[2];
  const int*   attn        = (const int*)d_in[3];
  const int*   starts      = (const int*)d_in[4];
  const int*   ends        = (const int*)d_in[5];
  const int*   math_labels = (const int*)d_in[7];
  const float* A_matrices  = (const float*)d_in[9];
  const float* B_matrices  = (const float*)d_in[10];
  const float* bias        = (const float*)d_in[11];
  const float* W_lm        = (const float*)d_in[12];
  float* out = (float*)d_out;

  char* ws = (char*)d_ws;
  size_t off = 0;
  intx4* Wf   = (intx4*)ws;                 off += (size_t)NQG * Vv * 16;      // 131 MB
  intx4* Aq   = (intx4*)(ws + off);         off += (size_t)NQG * M_PAD * 16;   // 10.5 MB
  float* part = (float*)(ws + off);         off += (size_t)HC * PART_STRIDE * 4;
  int*   labels = (int*)(ws + off);         off += (size_t)M_PAD * 4;
  float* llog   = (float*)(ws + off);       off += (size_t)M_PAD * 4;
  float* pmax   = (float*)(ws + off);       off += (size_t)M_PAD * NT_N * 4;
  float* psum   = (float*)(ws + off);       off += (size_t)M_PAD * NT_N * 4;
  float* nll    = (float*)(ws + off);       off += (size_t)M_PAD * 4;

  {
    dim3 ga((M_MAIN + 255) / 256, NQG);
    k_convA<<<ga, 256, 0, stream>>>(last_hidden, Aq);
  }
  k_inter2<<<Bb * NSEG * HC, 256, 0, stream>>>(k_hidden, B_matrices, starts, part);
  k_trans<<<Bb * NSEG * 8, 256, 0, stream>>>(part, A_matrices, bias, Aq);
  k_labels<<<(M_PAD + 255) / 256, 256, 0, stream>>>(input_ids, math_labels, labels, llog, Aq);
  {
    dim3 gw(Vv / 256, NQG);
    k_convW<<<gw, 256, 0, stream>>>(W_lm, Wf);
  }
  k_gemm_mx3<<<NWG, 512, 0, stream>>>(Aq, Wf, labels, pmax, psum, llog);
  k_fin<<<(M_REAL + 3) / 4, 256, 0, stream>>>(pmax, psum, llog, nll);
  k_loss<<<1, 256, 0, stream>>>(nll, starts, ends, attn, out);
}

// Round 8
// 742.313 us; speedup vs baseline: 1.0002x; 1.0002x over previous
//
#include <hip/hip_runtime.h>

#define NSEG 16
#define CH   16
#define Bb   2
#define Ss   1024
#define Hh   4096
#define Vv   32000
#define SMm  256
#define Rr   256

#define M_MAIN 2046   // Bb*(Ss-1)
#define M_MATH 512
#define M_REAL 2558
#define M_PAD  2560

#define BM 128
#define BN 128
#define BK 128
#define NT_M (M_PAD/BM)   // 20
#define NT_N (Vv/BN)      // 250
#define KT   (Hh/BK)      // 32
#define NWG  (NT_M*NT_N)  // 5000
#define NQG  (Hh/16)      // 256 global 16-k groups

#define HC   8
#define HCL  (Hh/HC)      // 512
#define PART_STRIDE (Bb*NSEG*CH*Rr)

typedef __attribute__((ext_vector_type(4))) float    floatx4;
typedef __attribute__((ext_vector_type(4))) int      intx4;
typedef __attribute__((ext_vector_type(8))) int      intx8;

#define ASCALE 16.f
#define WSCALE 256.f
#define DESCALE (1.f/(16.f*256.f))

template<bool W>
__device__ __forceinline__ int cvtpk(float a, float b, int old) {
  return __builtin_amdgcn_cvt_pk_fp8_f32(a, b, old, W);
}

__device__ __forceinline__ void gload_lds16(const void* g, void* l) {
  __builtin_amdgcn_global_load_lds((const __attribute__((address_space(1))) void*)g,
                                   (__attribute__((address_space(3))) void*)l, 16, 0, 0);
}

// ---------------- K0a: last_hidden -> fp8 A panel, [qgg][row] 16B groups (rows 0..2045) ----------------
__global__ __launch_bounds__(256) void k_convA(const float* __restrict__ lh, intx4* __restrict__ Aq) {
  int row = blockIdx.x * 256 + threadIdx.x;
  int qgg = blockIdx.y;                     // 0..255
  if (row >= M_MAIN) return;
  int b = row / (Ss - 1), s = row % (Ss - 1);
  const floatx4* src = (const floatx4*)(lh + ((size_t)(b * Ss + s)) * Hh + qgg * 16);
  floatx4 f0 = src[0], f1 = src[1], f2 = src[2], f3 = src[3];
  int p0 = cvtpk<false>(f0[0]*ASCALE, f0[1]*ASCALE, 0); p0 = cvtpk<true>(f0[2]*ASCALE, f0[3]*ASCALE, p0);
  int p1 = cvtpk<false>(f1[0]*ASCALE, f1[1]*ASCALE, 0); p1 = cvtpk<true>(f1[2]*ASCALE, f1[3]*ASCALE, p1);
  int p2 = cvtpk<false>(f2[0]*ASCALE, f2[1]*ASCALE, 0); p2 = cvtpk<true>(f2[2]*ASCALE, f2[3]*ASCALE, p2);
  int p3 = cvtpk<false>(f3[0]*ASCALE, f3[1]*ASCALE, 0); p3 = cvtpk<true>(f3[2]*ASCALE, f3[3]*ASCALE, p3);
  Aq[(size_t)qgg * M_PAD + row] = (intx4){p0, p1, p2, p3};
}

// ---------------- K0w: W fp32 -> fp8 Wf[qgg][v] 16B = W[16qgg..16qgg+15][v] * 256 ----------------
__global__ __launch_bounds__(256) void k_convW(const float* __restrict__ W, intx4* __restrict__ Wf) {
  int v = blockIdx.x * 256 + threadIdx.x;   // 125*256 = 32000 exactly
  int qgg = blockIdx.y;                     // 0..255
  const float* base = W + (size_t)(qgg * 16) * Vv + v;
  int p[4];
  #pragma unroll
  for (int q = 0; q < 4; ++q) {
    float e0 = base[(size_t)(4*q+0) * Vv] * WSCALE;
    float e1 = base[(size_t)(4*q+1) * Vv] * WSCALE;
    float e2 = base[(size_t)(4*q+2) * Vv] * WSCALE;
    float e3 = base[(size_t)(4*q+3) * Vv] * WSCALE;
    int pp = cvtpk<false>(e0, e1, 0);
    p[q] = cvtpk<true>(e2, e3, pp);
  }
  Wf[(size_t)qgg * Vv + v] = (intx4){p[0], p[1], p[2], p[3]};
}

// ---------------- K0b: per-H-chunk partials of inter, x staged in LDS ----------------
__global__ __launch_bounds__(256) void k_inter2(const float* __restrict__ kh, const float* __restrict__ Bm,
                                                const int* __restrict__ starts, float* __restrict__ part) {
  int bid = blockIdx.x;                 // Bb*NSEG*HC = 256
  int b = bid >> 7, seg = (bid >> 3) & 15, hc = bid & 7;
  int tid = threadIdx.x;                // = r
  __shared__ float sX[CH][HCL];         // 32 KB
  int st = starts[b];
  for (int i = tid; i < CH * (HCL / 4); i += 256) {
    int c = i / (HCL / 4), k4 = i % (HCL / 4);
    int pos = st + seg * CH + c;
    ((floatx4*)&sX[c][0])[k4] = *(const floatx4*)(kh + ((size_t)(b * Ss + pos)) * Hh + hc * HCL + 4 * k4);
  }
  __syncthreads();
  const floatx4* w = (const floatx4*)(Bm + ((size_t)(seg * Rr + tid)) * Hh + hc * HCL);
  float acc[CH];
  #pragma unroll
  for (int c = 0; c < CH; ++c) acc[c] = 0.f;
  for (int i = 0; i < HCL / 4; ++i) {
    floatx4 w4 = w[i];
    #pragma unroll
    for (int c = 0; c < CH; ++c)
      acc[c] += w4[0]*sX[c][4*i] + w4[1]*sX[c][4*i+1] + w4[2]*sX[c][4*i+2] + w4[3]*sX[c][4*i+3];
  }
  float* dst = part + (size_t)hc * PART_STRIDE + ((size_t)(b * NSEG + seg)) * CH * Rr;
  #pragma unroll
  for (int c = 0; c < CH; ++c) dst[c * Rr + tid] = acc[c];
}

// ---------------- K0c: trans = (sum_hc part) @ A^T + bias -> fp8 A panel rows 2046..2557 ----------------
__global__ __launch_bounds__(256) void k_trans(const float* __restrict__ part, const float* __restrict__ Am,
                                               const float* __restrict__ bias, intx4* __restrict__ Aq) {
  int bid = blockIdx.x;
  int b = bid >> 7, seg = (bid >> 3) & 15, ht = bid & 7;
  int tid = threadIdx.x;
  __shared__ float sI[CH][Rr];
  const float* ib = part + ((size_t)(b * NSEG + seg)) * CH * Rr;
  for (int i = tid; i < CH * Rr / 4; i += 256) {
    floatx4 s = ((const floatx4*)ib)[i];
    #pragma unroll
    for (int hc = 1; hc < HC; ++hc)
      s += ((const floatx4*)(ib + (size_t)hc * PART_STRIDE))[i];
    ((floatx4*)&sI[0][0])[i] = s;
  }
  __syncthreads();
  unsigned char* Ab = (unsigned char*)Aq;
  for (int hh = 0; hh < 2; ++hh) {
    int h = (ht << 9) + (tid << 1) + hh;
    const floatx4* ar = (const floatx4*)(Am + ((size_t)(seg * Hh + h)) * Rr);
    float acc[CH];
    #pragma unroll
    for (int c = 0; c < CH; ++c) acc[c] = 0.f;
    for (int i = 0; i < Rr / 4; ++i) {
      floatx4 a4 = ar[i];
      #pragma unroll
      for (int c = 0; c < CH; ++c)
        acc[c] += a4[0]*sI[c][i*4] + a4[1]*sI[c][i*4+1] + a4[2]*sI[c][i*4+2] + a4[3]*sI[c][i*4+3];
    }
    float bv = bias[seg * Hh + h];
    #pragma unroll
    for (int c = 0; c < CH; ++c) {
      int row = M_MAIN + b * SMm + seg * CH + c;
      int pk = cvtpk<false>((acc[c] + bv) * ASCALE, 0.f, 0);
      Ab[(((size_t)(h >> 4)) * M_PAD + row) * 16 + (h & 15)] = (unsigned char)(pk & 0xFF);
    }
  }
}

// ---------------- K0d: labels, label-logit init, zero fp8 pad rows ----------------
__global__ __launch_bounds__(256) void k_labels(const int* __restrict__ input_ids, const int* __restrict__ mlab,
                                                int* __restrict__ labels, float* __restrict__ llog,
                                                intx4* __restrict__ Aq) {
  int t = blockIdx.x * 256 + threadIdx.x;
  if (t < M_PAD) {
    int lab;
    if (t < M_MAIN)      { int b = t / (Ss - 1), s = t % (Ss - 1); lab = input_ids[b * Ss + s + 1]; }
    else if (t < M_REAL) { lab = mlab[t - M_MAIN]; }
    else                 { lab = 0x7fffffff; }
    labels[t] = lab;
    llog[t] = 0.f;
  }
  if (t < 2 * NQG) {   // zero pad rows 2558,2559 across all 256 qgg
    int qgg = t >> 1, row = M_REAL + (t & 1);
    Aq[(size_t)qgg * M_PAD + row] = (intx4){0, 0, 0, 0};
  }
}

// ---------------- K1: MX-fp8 GEMM, 128x128 tile, 512 thr, 2-buffer counted-vmcnt, 2 blocks/CU ----------------
__global__ __launch_bounds__(512, 4) void k_gemm_mx4(const intx4* __restrict__ Aq, const intx4* __restrict__ Wf,
                                                     const int* __restrict__ labels, float* __restrict__ pmax,
                                                     float* __restrict__ psum, float* __restrict__ llog) {
  __shared__ intx4 As[2][8][BM];    // 32 KB  [buf][qg][row]
  __shared__ intx4 Bs[2][8][BN];    // 32 KB  [buf][qg][col]
  __shared__ float redM[BM * 2];
  __shared__ float redS[BM * 2];

  int bid = blockIdx.x;
  int mt = bid % NT_M, nt = bid / NT_M;   // mt-inner: 20 consecutive blocks share the W panel
  int m0 = mt * BM, n0 = nt * BN;
  int tid = threadIdx.x;
  int lane = tid & 63;
  int wid = tid >> 6;                     // 8 waves: 4 M x 2 N; wave-tile 32x64
  int wr = wid >> 1, wc = wid & 1;
  int l15 = lane & 15, l4 = lane >> 4;

  floatx4 acc[2][4];
  #pragma unroll
  for (int m = 0; m < 2; ++m)
    #pragma unroll
    for (int n = 0; n < 4; ++n) acc[m][n] = (floatx4){0.f, 0.f, 0.f, 0.f};

  // staging: 4 loads/thread/tile (A qg tq and tq+4; B same), running pointers
  int tq = tid >> 7, tr = tid & 127;      // qg 0..3, row/col 0..127
  const intx4* pA = Aq + (size_t)tq * M_PAD + m0 + tr;
  const intx4* pB = Wf + (size_t)tq * Vv + n0 + tr;

#define STAGE(bb) do {                                        \
    gload_lds16(pA,                 &As[bb][tq][tr]);         \
    gload_lds16(pA + 4 * (size_t)M_PAD, &As[bb][tq + 4][tr]); \
    gload_lds16(pB,                 &Bs[bb][tq][tr]);         \
    gload_lds16(pB + 4 * (size_t)Vv,    &Bs[bb][tq + 4][tr]); \
    pA += 8 * (size_t)M_PAD; pB += 8 * (size_t)Vv;            \
  } while (0)

  STAGE(0);
  STAGE(1);

  for (int kt = 0; kt < KT; ++kt) {
    int cb = kt & 1;
    if (kt < KT - 1) {
      asm volatile("s_waitcnt vmcnt(4)" ::: "memory");   // tile kt's 4 loads (oldest) done; kt+1's in flight
    } else {
      asm volatile("s_waitcnt vmcnt(0)" ::: "memory");
    }
    __builtin_amdgcn_s_barrier();                        // all waves' tile-kt loads landed
    __builtin_amdgcn_sched_barrier(0);

    intx8 a[2], b[4];
    #pragma unroll
    for (int m = 0; m < 2; ++m) {
      int row = wr * 32 + m * 16 + l15;
      intx4 lo = As[cb][2 * l4][row];
      intx4 hi = As[cb][2 * l4 + 1][row];
      a[m] = __builtin_shufflevector(lo, hi, 0, 1, 2, 3, 4, 5, 6, 7);
    }
    #pragma unroll
    for (int n = 0; n < 4; ++n) {
      int col = wc * 64 + n * 16 + l15;
      intx4 lo = Bs[cb][2 * l4][col];
      intx4 hi = Bs[cb][2 * l4 + 1][col];
      b[n] = __builtin_shufflevector(lo, hi, 0, 1, 2, 3, 4, 5, 6, 7);
    }

    __builtin_amdgcn_s_setprio(1);
    #pragma unroll
    for (int m = 0; m < 2; ++m)
      #pragma unroll
      for (int n = 0; n < 4; ++n)
        acc[m][n] = __builtin_amdgcn_mfma_scale_f32_16x16x128_f8f6f4(
            a[m], b[n], acc[m][n], 0, 0, 0, 0x7F7F7F7F, 0, 0x7F7F7F7F);
    __builtin_amdgcn_s_setprio(0);

    __builtin_amdgcn_s_barrier();                        // all waves done reading buf cb
    __builtin_amdgcn_sched_barrier(0);
    if (kt + 2 < KT) STAGE(cb);                          // refill the buffer just freed
  }
#undef STAGE

  // ---- descale (A*16, W*256) ----
  #pragma unroll
  for (int m = 0; m < 2; ++m)
    #pragma unroll
    for (int n = 0; n < 4; ++n) acc[m][n] *= DESCALE;

  // ---- epilogue: label logit scatter; C/D: col=lane&15, row=(lane>>4)*4+reg ----
  #pragma unroll
  for (int m = 0; m < 2; ++m) {
    #pragma unroll
    for (int r = 0; r < 4; ++r) {
      int grow = m0 + wr * 32 + m * 16 + l4 * 4 + r;
      int lab = (grow < M_REAL) ? labels[grow] : -1;
      #pragma unroll
      for (int n = 0; n < 4; ++n) {
        int gcol = n0 + wc * 64 + n * 16 + l15;
        if (lab == gcol) llog[grow] = acc[m][n][r];
      }
    }
  }
  float rm[2][4];
  #pragma unroll
  for (int m = 0; m < 2; ++m)
    #pragma unroll
    for (int r = 0; r < 4; ++r) {
      float v = fmaxf(fmaxf(acc[m][0][r], acc[m][1][r]), fmaxf(acc[m][2][r], acc[m][3][r]));
      v = fmaxf(v, __shfl_xor(v, 1));
      v = fmaxf(v, __shfl_xor(v, 2));
      v = fmaxf(v, __shfl_xor(v, 4));
      v = fmaxf(v, __shfl_xor(v, 8));
      rm[m][r] = v;
    }
  __syncthreads();    // re-sync before redM use (pipeline barriers consumed)
  if (l15 == 0) {
    #pragma unroll
    for (int m = 0; m < 2; ++m)
      #pragma unroll
      for (int r = 0; r < 4; ++r)
        redM[(wr * 32 + m * 16 + l4 * 4 + r) * 2 + wc] = rm[m][r];
  }
  __syncthreads();
  #pragma unroll
  for (int m = 0; m < 2; ++m)
    #pragma unroll
    for (int r = 0; r < 4; ++r) {
      int row = wr * 32 + m * 16 + l4 * 4 + r;
      float tmx = fmaxf(redM[row * 2], redM[row * 2 + 1]);
      float s = 0.f;
      #pragma unroll
      for (int n = 0; n < 4; ++n) s += __expf(acc[m][n][r] - tmx);
      s += __shfl_xor(s, 1);
      s += __shfl_xor(s, 2);
      s += __shfl_xor(s, 4);
      s += __shfl_xor(s, 8);
      rm[m][r] = s;
    }
  if (l15 == 0) {
    #pragma unroll
    for (int m = 0; m < 2; ++m)
      #pragma unroll
      for (int r = 0; r < 4; ++r)
        redS[(wr * 32 + m * 16 + l4 * 4 + r) * 2 + wc] = rm[m][r];
  }
  __syncthreads();
  if (tid < BM) {
    int grow = m0 + tid;
    if (grow < M_REAL) {
      float tmx = fmaxf(redM[tid * 2], redM[tid * 2 + 1]);
      float s = redS[tid * 2] + redS[tid * 2 + 1];
      pmax[(size_t)grow * NT_N + nt] = tmx;
      psum[(size_t)grow * NT_N + nt] = s;
    }
  }
}

// ---------------- K2: combine partials -> nll per row ----------------
__global__ __launch_bounds__(256) void k_fin(const float* __restrict__ pmax, const float* __restrict__ psum,
                                             const float* __restrict__ llog, float* __restrict__ nll) {
  int row = blockIdx.x * 4 + (threadIdx.x >> 6);
  int lane = threadIdx.x & 63;
  if (row >= M_REAL) return;
  float m = -3.4e38f;
  for (int t = lane; t < NT_N; t += 64) m = fmaxf(m, pmax[(size_t)row * NT_N + t]);
  #pragma unroll
  for (int d = 1; d < 64; d <<= 1) m = fmaxf(m, __shfl_xor(m, d));
  float s = 0.f;
  for (int t = lane; t < NT_N; t += 64)
    s += psum[(size_t)row * NT_N + t] * __expf(pmax[(size_t)row * NT_N + t] - m);
  #pragma unroll
  for (int d = 1; d < 64; d <<= 1) s += __shfl_xor(s, d);
  if (lane == 0) nll[row] = logf(s) + m - llog[row];
}

// ---------------- K3: masks, means, A_losses -> 20 outputs ----------------
__global__ __launch_bounds__(256) void k_loss(const float* __restrict__ nll, const int* __restrict__ starts,
                                              const int* __restrict__ ends, const int* __restrict__ attn,
                                              float* __restrict__ out) {
  __shared__ float rA[256], rB[256], rC[256], rD[256];
  __shared__ float smath[M_MATH];
  __shared__ float rl[2];
  int tid = threadIdx.x;
  for (int b = 0; b < 2; ++b) {
    float p = 0.f;
    for (int i = tid; i < Ss; i += 256) p += (float)attn[b * Ss + i];
    rA[tid] = p;
    __syncthreads();
    if (tid == 0) { float t = 0.f; for (int i = 0; i < 256; ++i) t += rA[i]; rl[b] = t; }
    __syncthreads();
  }
  float ss = 0.f, sc = 0.f, fs = 0.f, fc = 0.f;
  int st0 = starts[0], st1 = starts[1], en0 = ends[0], en1 = ends[1];
  for (int r = tid; r < M_MAIN; r += 256) {
    int b = r / (Ss - 1), idx = r % (Ss - 1);
    int st = b ? st1 : st0, en = b ? en1 : en0;
    int rlen = (int)rl[b];
    float v = nll[r];
    if (idx >= st - 1 && idx <= en - 1) { ss += v; sc += 1.f; }
    if (idx >= en && idx < rlen - 1)    { fs += v; fc += 1.f; }
  }
  rA[tid] = ss; rB[tid] = sc; rC[tid] = fs; rD[tid] = fc;
  for (int j = tid; j < M_MATH; j += 256) smath[j] = nll[M_MAIN + j];
  __syncthreads();
  if (tid == 0) {
    float SS = 0.f, SC = 0.f, FS = 0.f, FC = 0.f;
    for (int i = 0; i < 256; ++i) { SS += rA[i]; SC += rB[i]; FS += rC[i]; FC += rD[i]; }
    float MS = 0.f;
    for (int j = 0; j < M_MATH; ++j) MS += smath[j];
    float math_loss = MS / (float)M_MATH;
    float simple = (SC > 0.f) ? SS / fmaxf(SC, 1.f) : 0.f;
    float fin    = (FC > 0.f) ? FS / fmaxf(FC, 1.f) : 0.f;
    out[0] = 0.5f * math_loss + 0.5f * simple + 0.4f * fin;
    out[1] = math_loss;
    out[2] = simple;
    out[3] = fin;
    for (int seg = 0; seg < NSEG; ++seg) {
      float a = 0.f;
      for (int b = 0; b < 2; ++b)
        for (int c = 0; c < CH; ++c) a += smath[b * SMm + seg * CH + c];
      out[4 + seg] = a / 32.f;
    }
  }
}

extern "C" void kernel_launch(void* const* d_in, const int* in_sizes, int n_in,
                              void* d_out, int out_size, void* d_ws, size_t ws_size,
                              hipStream_t stream) {
  const float* k_hidden    = (const float*)d_in[0];
  const float* last_hidden = (const float*)d_in[1];
  const int*   input_ids   = (const int*)d_in[2];
  const int*   attn        = (const int*)d_in[3];
  const int*   starts      = (const int*)d_in[4];
  const int*   ends        = (const int*)d_in[5];
  const int*   math_labels = (const int*)d_in[7];
  const float* A_matrices  = (const float*)d_in[9];
  const float* B_matrices  = (const float*)d_in[10];
  const float* bias        = (const float*)d_in[11];
  const float* W_lm        = (const float*)d_in[12];
  float* out = (float*)d_out;

  char* ws = (char*)d_ws;
  size_t off = 0;
  intx4* Wf   = (intx4*)ws;                 off += (size_t)NQG * Vv * 16;      // 131 MB
  intx4* Aq   = (intx4*)(ws + off);         off += (size_t)NQG * M_PAD * 16;   // 10.5 MB
  float* part = (float*)(ws + off);         off += (size_t)HC * PART_STRIDE * 4;
  int*   labels = (int*)(ws + off);         off += (size_t)M_PAD * 4;
  float* llog   = (float*)(ws + off);       off += (size_t)M_PAD * 4;
  float* pmax   = (float*)(ws + off);       off += (size_t)M_PAD * NT_N * 4;
  float* psum   = (float*)(ws + off);       off += (size_t)M_PAD * NT_N * 4;
  float* nll    = (float*)(ws + off);       off += (size_t)M_PAD * 4;

  {
    dim3 ga((M_MAIN + 255) / 256, NQG);
    k_convA<<<ga, 256, 0, stream>>>(last_hidden, Aq);
  }
  k_inter2<<<Bb * NSEG * HC, 256, 0, stream>>>(k_hidden, B_matrices, starts, part);
  k_trans<<<Bb * NSEG * 8, 256, 0, stream>>>(part, A_matrices, bias, Aq);
  k_labels<<<(M_PAD + 255) / 256, 256, 0, stream>>>(input_ids, math_labels, labels, llog, Aq);
  {
    dim3 gw(Vv / 256, NQG);
    k_convW<<<gw, 256, 0, stream>>>(W_lm, Wf);
  }
  k_gemm_mx4<<<NWG, 512, 0, stream>>>(Aq, Wf, labels, pmax, psum, llog);
  k_fin<<<(M_REAL + 3) / 4, 256, 0, stream>>>(pmax, psum, llog, nll);
  k_loss<<<1, 256, 0, stream>>>(nll, starts, ends, attn, out);
}

// Round 9
// 590.107 us; speedup vs baseline: 1.2582x; 1.2579x over previous
//
#include <hip/hip_runtime.h>

#define NSEG 16
#define CH   16
#define Bb   2
#define Ss   1024
#define Hh   4096
#define Vv   32000
#define SMm  256
#define Rr   256

#define M_MAIN 2046   // Bb*(Ss-1)
#define M_MATH 512
#define M_REAL 2558
#define M_PAD  2560

#define BM 256
#define BN 128
#define BK 128
#define NT_M (M_PAD/BM)   // 10
#define NT_N (Vv/BN)      // 250
#define KT   (Hh/BK)      // 32
#define NWG  (NT_M*NT_N)  // 2500
#define NQG  (Hh/16)      // 256 global 16-k groups

#define HC   8
#define HCL  (Hh/HC)      // 512
#define PART_STRIDE (Bb*NSEG*CH*Rr)

typedef __attribute__((ext_vector_type(4))) float    floatx4;
typedef __attribute__((ext_vector_type(4))) int      intx4;
typedef __attribute__((ext_vector_type(8))) int      intx8;

#define ASCALE 16.f
#define WSCALE 256.f
#define DESCALE (1.f/(16.f*256.f))

template<bool W>
__device__ __forceinline__ int cvtpk(float a, float b, int old) {
  return __builtin_amdgcn_cvt_pk_fp8_f32(a, b, old, W);
}

__device__ __forceinline__ void gload_lds16(const void* g, void* l) {
  __builtin_amdgcn_global_load_lds((const __attribute__((address_space(1))) void*)g,
                                   (__attribute__((address_space(3))) void*)l, 16, 0, 0);
}

// ---------------- K0a: last_hidden -> fp8 A panel, [qgg][row] 16B groups (rows 0..2045) ----------------
__global__ __launch_bounds__(256) void k_convA(const float* __restrict__ lh, intx4* __restrict__ Aq) {
  int row = blockIdx.x * 256 + threadIdx.x;
  int qgg = blockIdx.y;                     // 0..255
  if (row >= M_MAIN) return;
  int b = row / (Ss - 1), s = row % (Ss - 1);
  const floatx4* src = (const floatx4*)(lh + ((size_t)(b * Ss + s)) * Hh + qgg * 16);
  floatx4 f0 = src[0], f1 = src[1], f2 = src[2], f3 = src[3];
  int p0 = cvtpk<false>(f0[0]*ASCALE, f0[1]*ASCALE, 0); p0 = cvtpk<true>(f0[2]*ASCALE, f0[3]*ASCALE, p0);
  int p1 = cvtpk<false>(f1[0]*ASCALE, f1[1]*ASCALE, 0); p1 = cvtpk<true>(f1[2]*ASCALE, f1[3]*ASCALE, p1);
  int p2 = cvtpk<false>(f2[0]*ASCALE, f2[1]*ASCALE, 0); p2 = cvtpk<true>(f2[2]*ASCALE, f2[3]*ASCALE, p2);
  int p3 = cvtpk<false>(f3[0]*ASCALE, f3[1]*ASCALE, 0); p3 = cvtpk<true>(f3[2]*ASCALE, f3[3]*ASCALE, p3);
  Aq[(size_t)qgg * M_PAD + row] = (intx4){p0, p1, p2, p3};
}

// ---------------- K0w: W fp32 -> fp8 Wf[qgg][v] 16B = W[16qgg..16qgg+15][v] * 256 ----------------
__global__ __launch_bounds__(256) void k_convW(const float* __restrict__ W, intx4* __restrict__ Wf) {
  int v = blockIdx.x * 256 + threadIdx.x;   // 125*256 = 32000 exactly
  int qgg = blockIdx.y;                     // 0..255
  const float* base = W + (size_t)(qgg * 16) * Vv + v;
  int p[4];
  #pragma unroll
  for (int q = 0; q < 4; ++q) {
    float e0 = base[(size_t)(4*q+0) * Vv] * WSCALE;
    float e1 = base[(size_t)(4*q+1) * Vv] * WSCALE;
    float e2 = base[(size_t)(4*q+2) * Vv] * WSCALE;
    float e3 = base[(size_t)(4*q+3) * Vv] * WSCALE;
    int pp = cvtpk<false>(e0, e1, 0);
    p[q] = cvtpk<true>(e2, e3, pp);
  }
  Wf[(size_t)qgg * Vv + v] = (intx4){p[0], p[1], p[2], p[3]};
}

// ---------------- K0b: per-H-chunk partials of inter, x staged in LDS ----------------
__global__ __launch_bounds__(256) void k_inter2(const float* __restrict__ kh, const float* __restrict__ Bm,
                                                const int* __restrict__ starts, float* __restrict__ part) {
  int bid = blockIdx.x;                 // Bb*NSEG*HC = 256
  int b = bid >> 7, seg = (bid >> 3) & 15, hc = bid & 7;
  int tid = threadIdx.x;                // = r
  __shared__ float sX[CH][HCL];         // 32 KB
  int st = starts[b];
  for (int i = tid; i < CH * (HCL / 4); i += 256) {
    int c = i / (HCL / 4), k4 = i % (HCL / 4);
    int pos = st + seg * CH + c;
    ((floatx4*)&sX[c][0])[k4] = *(const floatx4*)(kh + ((size_t)(b * Ss + pos)) * Hh + hc * HCL + 4 * k4);
  }
  __syncthreads();
  const floatx4* w = (const floatx4*)(Bm + ((size_t)(seg * Rr + tid)) * Hh + hc * HCL);
  float acc[CH];
  #pragma unroll
  for (int c = 0; c < CH; ++c) acc[c] = 0.f;
  for (int i = 0; i < HCL / 4; ++i) {
    floatx4 w4 = w[i];
    #pragma unroll
    for (int c = 0; c < CH; ++c)
      acc[c] += w4[0]*sX[c][4*i] + w4[1]*sX[c][4*i+1] + w4[2]*sX[c][4*i+2] + w4[3]*sX[c][4*i+3];
  }
  float* dst = part + (size_t)hc * PART_STRIDE + ((size_t)(b * NSEG + seg)) * CH * Rr;
  #pragma unroll
  for (int c = 0; c < CH; ++c) dst[c * Rr + tid] = acc[c];
}

// ---------------- K0c: trans = (sum_hc part) @ A^T + bias -> fp8 A panel rows 2046..2557 ----------------
__global__ __launch_bounds__(256) void k_trans(const float* __restrict__ part, const float* __restrict__ Am,
                                               const float* __restrict__ bias, intx4* __restrict__ Aq) {
  int bid = blockIdx.x;
  int b = bid >> 7, seg = (bid >> 3) & 15, ht = bid & 7;
  int tid = threadIdx.x;
  __shared__ float sI[CH][Rr];
  const float* ib = part + ((size_t)(b * NSEG + seg)) * CH * Rr;
  for (int i = tid; i < CH * Rr / 4; i += 256) {
    floatx4 s = ((const floatx4*)ib)[i];
    #pragma unroll
    for (int hc = 1; hc < HC; ++hc)
      s += ((const floatx4*)(ib + (size_t)hc * PART_STRIDE))[i];
    ((floatx4*)&sI[0][0])[i] = s;
  }
  __syncthreads();
  unsigned char* Ab = (unsigned char*)Aq;
  for (int hh = 0; hh < 2; ++hh) {
    int h = (ht << 9) + (tid << 1) + hh;
    const floatx4* ar = (const floatx4*)(Am + ((size_t)(seg * Hh + h)) * Rr);
    float acc[CH];
    #pragma unroll
    for (int c = 0; c < CH; ++c) acc[c] = 0.f;
    for (int i = 0; i < Rr / 4; ++i) {
      floatx4 a4 = ar[i];
      #pragma unroll
      for (int c = 0; c < CH; ++c)
        acc[c] += a4[0]*sI[c][i*4] + a4[1]*sI[c][i*4+1] + a4[2]*sI[c][i*4+2] + a4[3]*sI[c][i*4+3];
    }
    float bv = bias[seg * Hh + h];
    #pragma unroll
    for (int c = 0; c < CH; ++c) {
      int row = M_MAIN + b * SMm + seg * CH + c;
      int pk = cvtpk<false>((acc[c] + bv) * ASCALE, 0.f, 0);
      Ab[(((size_t)(h >> 4)) * M_PAD + row) * 16 + (h & 15)] = (unsigned char)(pk & 0xFF);
    }
  }
}

// ---------------- K0d: labels, label-logit init, zero fp8 pad rows ----------------
__global__ __launch_bounds__(256) void k_labels(const int* __restrict__ input_ids, const int* __restrict__ mlab,
                                                int* __restrict__ labels, float* __restrict__ llog,
                                                intx4* __restrict__ Aq) {
  int t = blockIdx.x * 256 + threadIdx.x;
  if (t < M_PAD) {
    int lab;
    if (t < M_MAIN)      { int b = t / (Ss - 1), s = t % (Ss - 1); lab = input_ids[b * Ss + s + 1]; }
    else if (t < M_REAL) { lab = mlab[t - M_MAIN]; }
    else                 { lab = 0x7fffffff; }
    labels[t] = lab;
    llog[t] = 0.f;
  }
  if (t < 2 * NQG) {   // zero pad rows 2558,2559 across all 256 qgg
    int qgg = t >> 1, row = M_REAL + (t & 1);
    Aq[(size_t)qgg * M_PAD + row] = (intx4){0, 0, 0, 0};
  }
}

// ---------------- K1: MX-fp8 GEMM, 256x128 tile, 3-buffer counted-vmcnt pipeline, XCD-bijective swizzle ----------------
__global__ __launch_bounds__(512, 2) void k_gemm_mx2(const intx4* __restrict__ Aq, const intx4* __restrict__ Wf,
                                                     const int* __restrict__ labels, float* __restrict__ pmax,
                                                     float* __restrict__ psum, float* __restrict__ llog) {
  __shared__ intx4 As[3][8][BM];    // 3 x 32 KB  [buf][qg][row]
  __shared__ intx4 Bs[3][8][BN];    // 3 x 16 KB  [buf][qg][col]
  __shared__ float redM[BM * 2];
  __shared__ float redS[BM * 2];

  // Bijective XCD swizzle (m204): hardware assigns XCD ~ bid%8. Give each XCD a
  // CONTIGUOUS swz range so a Wf panel's 10 mt-blocks live on ONE XCD's L2.
  // NWG=2500: XCDs 0-3 own 313 blocks, XCDs 4-7 own 312.
  int bid = blockIdx.x;
  int xcd = bid & 7, loc = bid >> 3;
  int swz = (xcd < 4) ? (xcd * 313 + loc) : (1252 + (xcd - 4) * 312 + loc);
  int mt = swz % NT_M, nt = swz / NT_M;   // mt-inner within the XCD's range
  int m0 = mt * BM, n0 = nt * BN;
  int tid = threadIdx.x;
  int lane = tid & 63;
  int wid = tid >> 6;                     // 8 waves: 4 M x 2 N
  int wr = wid >> 1, wc = wid & 1;
  int l15 = lane & 15, l4 = lane >> 4;

  floatx4 acc[4][4];
  #pragma unroll
  for (int m = 0; m < 4; ++m)
    #pragma unroll
    for (int n = 0; n < 4; ++n) acc[m][n] = (floatx4){0.f, 0.f, 0.f, 0.f};

  // stage tile tt (K-rows kt*8..kt*8+7) into buffer bb: 6 gloads/thread (A:4, B:2)
#define STAGE(tt, bb) do {                                                              \
    const intx4* ab_ = Aq + (size_t)(tt) * 8 * M_PAD;                                   \
    _Pragma("unroll")                                                                   \
    for (int it_ = 0; it_ < 4; ++it_) {                                                 \
      int s_ = it_ * 512 + tid;                                                         \
      gload_lds16(ab_ + ((size_t)(s_ >> 8) * M_PAD + m0 + (s_ & 255)),                  \
                  (void*)(&As[bb][0][0] + s_));                                         \
    }                                                                                   \
    const intx4* wb_ = Wf + (size_t)(tt) * 8 * Vv;                                      \
    _Pragma("unroll")                                                                   \
    for (int it_ = 0; it_ < 2; ++it_) {                                                 \
      int s_ = it_ * 512 + tid;                                                         \
      gload_lds16(wb_ + ((size_t)(s_ >> 7) * Vv + n0 + (s_ & 127)),                     \
                  (void*)(&Bs[bb][0][0] + s_));                                         \
    }                                                                                   \
  } while (0)

  STAGE(0, 0);          // oldest 6 loads
  STAGE(1, 1);          // next 6
  int cur = 0;

  for (int kt = 0; kt < KT; ++kt) {
    if (kt < KT - 1) {
      asm volatile("s_waitcnt vmcnt(6)" ::: "memory");   // tile kt's 6 loads (oldest) done; kt+1's stay in flight
    } else {
      asm volatile("s_waitcnt vmcnt(0)" ::: "memory");   // peeled drain for the last tile
    }
    __builtin_amdgcn_s_barrier();                        // all waves' tile-kt loads complete
    __builtin_amdgcn_sched_barrier(0);

    intx8 a[4], b[4];
    #pragma unroll
    for (int m = 0; m < 4; ++m) {
      int row = wr * 64 + m * 16 + l15;
      intx4 lo = As[cur][2 * l4][row];
      intx4 hi = As[cur][2 * l4 + 1][row];
      a[m] = __builtin_shufflevector(lo, hi, 0, 1, 2, 3, 4, 5, 6, 7);
    }
    #pragma unroll
    for (int n = 0; n < 4; ++n) {
      int col = wc * 64 + n * 16 + l15;
      intx4 lo = Bs[cur][2 * l4][col];
      intx4 hi = Bs[cur][2 * l4 + 1][col];
      b[n] = __builtin_shufflevector(lo, hi, 0, 1, 2, 3, 4, 5, 6, 7);
    }

    if (kt + 2 < KT) STAGE(kt + 2, (cur + 2) % 3);       // depth-2 prefetch into the free buffer

    __builtin_amdgcn_s_setprio(1);
    #pragma unroll
    for (int m = 0; m < 4; ++m)
      #pragma unroll
      for (int n = 0; n < 4; ++n)
        acc[m][n] = __builtin_amdgcn_mfma_scale_f32_16x16x128_f8f6f4(
            a[m], b[n], acc[m][n], 0, 0, 0, 0x7F7F7F7F, 0, 0x7F7F7F7F);
    __builtin_amdgcn_s_setprio(0);

    cur = (cur + 1) % 3;
  }
#undef STAGE

  // ---- descale (A*16, W*256) ----
  #pragma unroll
  for (int m = 0; m < 4; ++m)
    #pragma unroll
    for (int n = 0; n < 4; ++n) acc[m][n] *= DESCALE;

  __syncthreads();   // pipeline fully done before epilogue cross-wave LDS use

  // ---- epilogue: label logit scatter; C/D: col=lane&15, row=(lane>>4)*4+reg ----
  #pragma unroll
  for (int m = 0; m < 4; ++m) {
    #pragma unroll
    for (int r = 0; r < 4; ++r) {
      int grow = m0 + wr * 64 + m * 16 + l4 * 4 + r;
      int lab = (grow < M_REAL) ? labels[grow] : -1;
      #pragma unroll
      for (int n = 0; n < 4; ++n) {
        int gcol = n0 + wc * 64 + n * 16 + l15;
        if (lab == gcol) llog[grow] = acc[m][n][r];
      }
    }
  }
  float rm[4][4];
  #pragma unroll
  for (int m = 0; m < 4; ++m)
    #pragma unroll
    for (int r = 0; r < 4; ++r) {
      float v = fmaxf(fmaxf(acc[m][0][r], acc[m][1][r]), fmaxf(acc[m][2][r], acc[m][3][r]));
      v = fmaxf(v, __shfl_xor(v, 1));
      v = fmaxf(v, __shfl_xor(v, 2));
      v = fmaxf(v, __shfl_xor(v, 4));
      v = fmaxf(v, __shfl_xor(v, 8));
      rm[m][r] = v;
    }
  if (l15 == 0) {
    #pragma unroll
    for (int m = 0; m < 4; ++m)
      #pragma unroll
      for (int r = 0; r < 4; ++r)
        redM[(wr * 64 + m * 16 + l4 * 4 + r) * 2 + wc] = rm[m][r];
  }
  __syncthreads();
  #pragma unroll
  for (int m = 0; m < 4; ++m)
    #pragma unroll
    for (int r = 0; r < 4; ++r) {
      int row = wr * 64 + m * 16 + l4 * 4 + r;
      float tmx = fmaxf(redM[row * 2], redM[row * 2 + 1]);
      float s = 0.f;
      #pragma unroll
      for (int n = 0; n < 4; ++n) s += __expf(acc[m][n][r] - tmx);
      s += __shfl_xor(s, 1);
      s += __shfl_xor(s, 2);
      s += __shfl_xor(s, 4);
      s += __shfl_xor(s, 8);
      rm[m][r] = s;
    }
  if (l15 == 0) {
    #pragma unroll
    for (int m = 0; m < 4; ++m)
      #pragma unroll
      for (int r = 0; r < 4; ++r)
        redS[(wr * 64 + m * 16 + l4 * 4 + r) * 2 + wc] = rm[m][r];
  }
  __syncthreads();
  if (tid < BM) {
    int grow = m0 + tid;
    if (grow < M_REAL) {
      float tmx = fmaxf(redM[tid * 2], redM[tid * 2 + 1]);
      float s = redS[tid * 2] + redS[tid * 2 + 1];
      pmax[(size_t)grow * NT_N + nt] = tmx;
      psum[(size_t)grow * NT_N + nt] = s;
    }
  }
}

// ---------------- K2: combine partials -> nll per row ----------------
__global__ __launch_bounds__(256) void k_fin(const float* __restrict__ pmax, const float* __restrict__ psum,
                                             const float* __restrict__ llog, float* __restrict__ nll) {
  int row = blockIdx.x * 4 + (threadIdx.x >> 6);
  int lane = threadIdx.x & 63;
  if (row >= M_REAL) return;
  float m = -3.4e38f;
  for (int t = lane; t < NT_N; t += 64) m = fmaxf(m, pmax[(size_t)row * NT_N + t]);
  #pragma unroll
  for (int d = 1; d < 64; d <<= 1) m = fmaxf(m, __shfl_xor(m, d));
  float s = 0.f;
  for (int t = lane; t < NT_N; t += 64)
    s += psum[(size_t)row * NT_N + t] * __expf(pmax[(size_t)row * NT_N + t] - m);
  #pragma unroll
  for (int d = 1; d < 64; d <<= 1) s += __shfl_xor(s, d);
  if (lane == 0) nll[row] = logf(s) + m - llog[row];
}

// ---------------- K3: masks, means, A_losses -> 20 outputs ----------------
__global__ __launch_bounds__(256) void k_loss(const float* __restrict__ nll, const int* __restrict__ starts,
                                              const int* __restrict__ ends, const int* __restrict__ attn,
                                              float* __restrict__ out) {
  __shared__ float rA[256], rB[256], rC[256], rD[256];
  __shared__ float smath[M_MATH];
  __shared__ float rl[2];
  int tid = threadIdx.x;
  for (int b = 0; b < 2; ++b) {
    float p = 0.f;
    for (int i = tid; i < Ss; i += 256) p += (float)attn[b * Ss + i];
    rA[tid] = p;
    __syncthreads();
    if (tid == 0) { float t = 0.f; for (int i = 0; i < 256; ++i) t += rA[i]; rl[b] = t; }
    __syncthreads();
  }
  float ss = 0.f, sc = 0.f, fs = 0.f, fc = 0.f;
  int st0 = starts[0], st1 = starts[1], en0 = ends[0], en1 = ends[1];
  for (int r = tid; r < M_MAIN; r += 256) {
    int b = r / (Ss - 1), idx = r % (Ss - 1);
    int st = b ? st1 : st0, en = b ? en1 : en0;
    int rlen = (int)rl[b];
    float v = nll[r];
    if (idx >= st - 1 && idx <= en - 1) { ss += v; sc += 1.f; }
    if (idx >= en && idx < rlen - 1)    { fs += v; fc += 1.f; }
  }
  rA[tid] = ss; rB[tid] = sc; rC[tid] = fs; rD[tid] = fc;
  for (int j = tid; j < M_MATH; j += 256) smath[j] = nll[M_MAIN + j];
  __syncthreads();
  if (tid == 0) {
    float SS = 0.f, SC = 0.f, FS = 0.f, FC = 0.f;
    for (int i = 0; i < 256; ++i) { SS += rA[i]; SC += rB[i]; FS += rC[i]; FC += rD[i]; }
    float MS = 0.f;
    for (int j = 0; j < M_MATH; ++j) MS += smath[j];
    float math_loss = MS / (float)M_MATH;
    float simple = (SC > 0.f) ? SS / fmaxf(SC, 1.f) : 0.f;
    float fin    = (FC > 0.f) ? FS / fmaxf(FC, 1.f) : 0.f;
    out[0] = 0.5f * math_loss + 0.5f * simple + 0.4f * fin;
    out[1] = math_loss;
    out[2] = simple;
    out[3] = fin;
    for (int seg = 0; seg < NSEG; ++seg) {
      float a = 0.f;
      for (int b = 0; b < 2; ++b)
        for (int c = 0; c < CH; ++c) a += smath[b * SMm + seg * CH + c];
      out[4 + seg] = a / 32.f;
    }
  }
}

extern "C" void kernel_launch(void* const* d_in, const int* in_sizes, int n_in,
                              void* d_out, int out_size, void* d_ws, size_t ws_size,
                              hipStream_t stream) {
  const float* k_hidden    = (const float*)d_in[0];
  const float* last_hidden = (const float*)d_in[1];
  const int*   input_ids   = (const int*)d_in[2];
  const int*   attn        = (const int*)d_in[3];
  const int*   starts      = (const int*)d_in[4];
  const int*   ends        = (const int*)d_in[5];
  const int*   math_labels = (const int*)d_in[7];
  const float* A_matrices  = (const float*)d_in[9];
  const float* B_matrices  = (const float*)d_in[10];
  const float* bias        = (const float*)d_in[11];
  const float* W_lm        = (const float*)d_in[12];
  float* out = (float*)d_out;

  char* ws = (char*)d_ws;
  size_t off = 0;
  intx4* Wf   = (intx4*)ws;                 off += (size_t)NQG * Vv * 16;      // 131 MB
  intx4* Aq   = (intx4*)(ws + off);         off += (size_t)NQG * M_PAD * 16;   // 10.5 MB
  float* part = (float*)(ws + off);         off += (size_t)HC * PART_STRIDE * 4;
  int*   labels = (int*)(ws + off);         off += (size_t)M_PAD * 4;
  float* llog   = (float*)(ws + off);       off += (size_t)M_PAD * 4;
  float* pmax   = (float*)(ws + off);       off += (size_t)M_PAD * NT_N * 4;
  float* psum   = (float*)(ws + off);       off += (size_t)M_PAD * NT_N * 4;
  float* nll    = (float*)(ws + off);       off += (size_t)M_PAD * 4;

  {
    dim3 ga((M_MAIN + 255) / 256, NQG);
    k_convA<<<ga, 256, 0, stream>>>(last_hidden, Aq);
  }
  k_inter2<<<Bb * NSEG * HC, 256, 0, stream>>>(k_hidden, B_matrices, starts, part);
  k_trans<<<Bb * NSEG * 8, 256, 0, stream>>>(part, A_matrices, bias, Aq);
  k_labels<<<(M_PAD + 255) / 256, 256, 0, stream>>>(input_ids, math_labels, labels, llog, Aq);
  {
    dim3 gw(Vv / 256, NQG);
    k_convW<<<gw, 256, 0, stream>>>(W_lm, Wf);
  }
  k_gemm_mx2<<<NWG, 512, 0, stream>>>(Aq, Wf, labels, pmax, psum, llog);
  k_fin<<<(M_REAL + 3) / 4, 256, 0, stream>>>(pmax, psum, llog, nll);
  k_loss<<<1, 256, 0, stream>>>(nll, starts, ends, attn, out);
}